// Round 14
// baseline (239.328 us; speedup 1.0000x reference)
//
#include <hip/hip_runtime.h>
#include <math.h>

#define N_NODES   16000
#define N_EDGES   512000
#define EMBED_DIM 28
#define NODE_DIM  128
#define NUM_BASIS 20

// Work items: edge chunks of 64 edges, node chunks of 2048 x_scalar elems.
#define EPB             64
#define EDGE_ITEMS      (N_EDGES / EPB)              // 8000
#define NODE_ITEM_ELEMS 2048
#define NODE_ITEMS      ((N_NODES * NODE_DIM) / NODE_ITEM_ELEMS)  // 1000
#define TOTAL_ITEMS     (EDGE_ITEMS + NODE_ITEMS)    // 9000

// LDS pattern table: 9 patterns x 64 edges x f4, +16B skew per pattern row.
#define PSTRIDE    260                                // dwords
#define PAT_DWORDS (8 * PSTRIDE + EPB * 4)            // 2336 dwords = 9.34 KB

#define GRID_BLOCKS 2816                              // 256 CU x 11 blocks

typedef float f32x4 __attribute__((ext_vector_type(4)));

// ---------------------------------------------------------------------------
// Persistent 1-wave blocks; dynamic work via atomic counter (or static
// stride if ctr == nullptr). No barriers anywhere: wave-synchronous LDS.
// ---------------------------------------------------------------------------
__global__ __launch_bounds__(64) void persist_kernel(
    const int*   __restrict__ at_no,
    const float* __restrict__ pos,
    const int*   __restrict__ eidx,
    const float* __restrict__ embed,
    const float* __restrict__ W,
    const float* __restrict__ bias,
    float*       __restrict__ x_scalar,
    float*       __restrict__ rbf,
    float*       __restrict__ fcut,
    float*       __restrict__ rsh,
    unsigned*                 ctr)
{
    const int t = threadIdx.x;

    __shared__ float sh_pat[PAT_DWORDS];        // 9.34 KB
    __shared__ float sh_rbf[EPB * NUM_BASIS];   // 5.12 KB

    // Loop-invariant selector offsets. Slot g = (o*15 + k)*64 + t;
    // period 15 in k (15*64 = 8*120); edge-offset advances +8 per outer o.
    int offs[15];
#pragma unroll
    for (int k = 0; k < 15; ++k) {
        int u = k * 64 + t;            // < 960
        int d = u / 120;               // 0..7
        int c = u - d * 120;
        int p;
        if (c < 32)      p = 0;
        else if (c < 80) p = 1 + (c - 32) % 3;
        else             p = 4 + (4 * (c - 80)) % 5;
        offs[k] = p * PSTRIDE + d * 4;
    }

    int it_static = blockIdx.x;        // fallback scheduler state

    for (;;) {
        int item;
        if (ctr) {
            if (t == 0) item = (int)atomicAdd(ctr, 1u);
            item = __shfl(item, 0);
        } else {
            item = it_static;
            it_static += GRID_BLOCKS;
        }
        if (item >= TOTAL_ITEMS) return;

        if (item < EDGE_ITEMS) {
            // ================= edge chunk: 64 edges, 1 per lane ===========
            const int e0 = item * EPB;
            const int e  = e0 + t;

            {
                int s  = eidx[e];
                int dn = eidx[N_EDGES + e];

                // reference permutes pos columns by [1,2,0]
                float ax = pos[s*3+1],  ay = pos[s*3+2],  az = pos[s*3+0];
                float bx = pos[dn*3+1], by = pos[dn*3+2], bz = pos[dn*3+0];
                float vx = ax - bx, vy = ay - by, vz = az - bz;
                float dist = sqrtf(vx*vx + vy*vy + vz*vz);
                float inv  = 1.0f / dist;
                float ux = vx*inv, uy = vy*inv, uz = vz*inv;

                const float S3  = 1.7320508075688772f;
                const float S5  = 2.2360679774997896f;
                const float S15 = 3.8729833462074170f;
                float s0 = S3 * ux, s1 = S3 * uy, s2 = S3 * uz;
                float t0 = S15 * ux * uz;
                float t1 = S15 * ux * uy;
                float t2 = S5  * (uy*uy - 0.5f*(ux*ux + uz*uz));
                float t3 = S15 * uy * uz;
                float t4 = 0.5f * S15 * (uz*uz - ux*ux);

                f32x4* pb = (f32x4*)sh_pat + t;      // pattern j at +j*65 f4
#define PW(j, a_, b_, c_, d_) { f32x4 v_; v_.x=a_; v_.y=b_; v_.z=c_; v_.w=d_; \
                                pb[(j) * (PSTRIDE/4)] = v_; }
                PW(0, 1.0f, 1.0f, 1.0f, 1.0f)
                PW(1, s0, s1, s2, s0)
                PW(2, s1, s2, s0, s1)
                PW(3, s2, s0, s1, s2)
                PW(4, t0, t1, t2, t3)
                PW(5, t1, t2, t3, t4)
                PW(6, t2, t3, t4, t0)
                PW(7, t3, t4, t0, t1)
                PW(8, t4, t0, t1, t2)
#undef PW

                // cutoff poly p=5: 1 - 21u^5 + 35u^6 - 15u^7
                float u  = dist * 0.2f;
                float u2 = u*u, u5 = u2*u2*u;
                float f  = 1.0f + u5*(-21.0f + u*(35.0f - 15.0f*u));
                fcut[e] = (u < 1.0f) ? f : 0.0f;

                // rbf via Chebyshev recurrence: sin(n*th), th = pi*dist/5
                float th = 0.62831853071795864769f * dist;
                float sn = __sinf(th), cs = __cosf(th);
                float twoc = 2.0f * cs;
                float kk = 0.6324555320336759f * inv;
                float sp = 0.0f, sc = sn;
                float* rb = sh_rbf + t * NUM_BASIS;
#pragma unroll
                for (int q = 0; q < NUM_BASIS; ++q) {
                    rb[q] = kk * sc;
                    float nx = twoc*sc - sp; sp = sc; sc = nx;
                }
            }
            // 1 wave: LDS writes->reads ordered by lgkmcnt, no barrier.

            // rbf writeout: 64 edges x 20 = 320 f4, 5 per lane, coalesced
            {
                const f32x4* ls = (const f32x4*)sh_rbf;
                f32x4* go = (f32x4*)(rbf + (size_t)e0 * NUM_BASIS);
#pragma unroll
                for (int q = 0; q < 5; ++q)
                    go[q * 64 + t] = ls[q * 64 + t];
            }

            // rsh store loop: 8 outer x 15, 120 f4 stores per lane
            {
                float* outb = rsh + (size_t)e0 * 480 + (size_t)t * 4;
                int base = 0;                // +32 dwords (8 edges) per outer
#pragma unroll 1
                for (int o = 0; o < 8; ++o) {
#pragma unroll
                    for (int k = 0; k < 15; ++k) {
                        f32x4 v = *(const f32x4*)(sh_pat + base + offs[k]);
                        *(f32x4*)(outb + (size_t)k * 256) = v;  // 64 f4 step
                    }
                    base += 32;
                    outb += 15 * 256;
                }
            }
        } else {
            // ================= node chunk: 2048 x_scalar elems ============
            const int nb = (item - EDGE_ITEMS) * NODE_ITEM_ELEMS;
#pragma unroll 1
            for (int j = 0; j < NODE_ITEM_ELEMS / 64; ++j) {   // 32 iters
                int idx  = nb + j * 64 + t;
                int node = idx >> 7;
                int d    = idx & 127;
                int a    = at_no[node];
                const float* er = embed + a * EMBED_DIM;
                const float* wr = W + d * EMBED_DIM;
                float sum = bias[d];
#pragma unroll
                for (int k = 0; k < EMBED_DIM; ++k)
                    sum = fmaf(er[k], wr[k], sum);
                x_scalar[idx] = sum;
            }
        }
    }
}

extern "C" void kernel_launch(void* const* d_in, const int* in_sizes, int n_in,
                              void* d_out, int out_size, void* d_ws, size_t ws_size,
                              hipStream_t stream) {
    const int*   at_no = (const int*)  d_in[0];
    const float* pos   = (const float*)d_in[1];
    const int*   eidx  = (const int*)  d_in[2];
    const float* embed = (const float*)d_in[3];
    const float* W     = (const float*)d_in[4];
    const float* b     = (const float*)d_in[5];

    float* out      = (float*)d_out;
    float* x_scalar = out;                                   // 16000*128
    float* rbf      = x_scalar + (size_t)N_NODES * NODE_DIM; // 512000*20
    float* fcut     = rbf + (size_t)N_EDGES * NUM_BASIS;     // 512000
    float* rsh      = fcut + N_EDGES;                        // 512000*480

    unsigned* ctr = nullptr;
    if (ws_size >= 4) {
        ctr = (unsigned*)d_ws;
        hipMemsetAsync(ctr, 0, 4, stream);   // graph-legal, deterministic
    }

    persist_kernel<<<GRID_BLOCKS, 64, 0, stream>>>(
        at_no, pos, eidx, embed, W, b, x_scalar, rbf, fcut, rsh, ctr);
}

// Round 15
// 200.624 us; speedup vs baseline: 1.1929x; 1.1929x over previous
//
#include <hip/hip_runtime.h>
#include <math.h>

#define N_NODES   16000
#define N_EDGES   512000
#define EMBED_DIM 28
#define NODE_DIM  128
#define NUM_BASIS 20

#define EPB    128                         // edges per chunk
#define CHUNKS 2                           // chunks per edge block (r13: 4)
#define EBLK   (N_EDGES / (EPB * CHUNKS))  // 2000 edge blocks

// node work at grid FRONT: 16000*128 = 2.048M elems = 500 blocks x 32 x 128
#define NODE_BLOCKS 500
#define NODE_CHUNKS 32

// LDS pattern table: 9 patterns, pattern j at dword offset j*PSTRIDE + e*4.
// PSTRIDE = 516 dwords (128 f4 + 16B skew). Double-buffered.
#define PSTRIDE 516
#define PAT_DWORDS (8 * PSTRIDE + EPB * 4)   // 4640 dwords = 18.56 KB

typedef float f32x4 __attribute__((ext_vector_type(4)));

// Raw barrier: LDS-ordering only. Global stores stay IN FLIGHT across it
// (unlike __syncthreads(), which drains vmcnt(0)).
#define LDS_BARRIER() do {                                    \
    __builtin_amdgcn_sched_barrier(0);                        \
    asm volatile("s_waitcnt lgkmcnt(0)" ::: "memory");        \
    __builtin_amdgcn_s_barrier();                             \
    __builtin_amdgcn_sched_barrier(0);                        \
} while (0)

// ---------------------------------------------------------------------------
// One kernel. Blocks < NODE_BLOCKS: x_scalar. Rest: edge blocks, CHUNKS
// chunks, chunk-major edge mapping: block b, chunk c -> edges (c*EBLK+b)*EPB.
// ---------------------------------------------------------------------------
__global__ __launch_bounds__(128) void fused_all_kernel(
    const int*   __restrict__ at_no,
    const float* __restrict__ pos,
    const int*   __restrict__ eidx,
    const float* __restrict__ embed,
    const float* __restrict__ W,
    const float* __restrict__ bias,
    float*       __restrict__ x_scalar,
    float*       __restrict__ rbf,
    float*       __restrict__ fcut,
    float*       __restrict__ rsh)
{
    const int t = threadIdx.x;

    if (blockIdx.x < NODE_BLOCKS) {
        // ---- node branch: x_scalar = embed[at_no] @ W.T + b ----
        int bid2 = blockIdx.x;
#pragma unroll 1
        for (int ch = 0; ch < NODE_CHUNKS; ++ch) {
            int idx  = (bid2 * NODE_CHUNKS + ch) * 128 + t;
            int node = idx >> 7;
            int d    = idx & 127;
            int a    = at_no[node];
            const float* er = embed + a * EMBED_DIM;
            const float* wr = W + d * EMBED_DIM;
            float sum = bias[d];
#pragma unroll
            for (int k = 0; k < EMBED_DIM; ++k)
                sum = fmaf(er[k], wr[k], sum);
            x_scalar[idx] = sum;
        }
        return;
    }

    __shared__ float sh_pat[2][PAT_DWORDS];   // 37.1 KB
    __shared__ float sh_rbf[EPB * 20];        // 10 KB

    const int blk = blockIdx.x - NODE_BLOCKS;

    // Loop-invariant selector offsets. Per-chunk f4 slot g = (i*15+k)*128+t;
    // period 15 in k (15*128 = 16*120); le advances +16 per outer iter.
    int offs[15];
#pragma unroll
    for (int k = 0; k < 15; ++k) {
        int u  = k * 128 + t;        // < 1920
        int d  = u / 120;
        int c  = u - d * 120;
        int p;
        if (c < 32)      p = 0;
        else if (c < 80) p = 1 + (c - 32) % 3;
        else             p = 4 + (4 * (c - 80)) % 5;
        offs[k] = p * PSTRIDE + d * 4;
    }

    // ---- prefetch chunk 0 inputs (chunk-major: ebase = (c*EBLK+blk)*EPB) --
    int s, dn;
    float ax, ay, az, bx, by, bz;
    {
        int e = blk * EPB + t;               // c = 0
        s  = eidx[e];
        dn = eidx[N_EDGES + e];
        ax = pos[s*3+1];  ay = pos[s*3+2];  az = pos[s*3+0];
        bx = pos[dn*3+1]; by = pos[dn*3+2]; bz = pos[dn*3+0];
    }

#pragma unroll 1
    for (int c = 0; c < CHUNKS; ++c) {
        const int ebase = (c * EBLK + blk) * EPB;
        const int ecur  = ebase + t;

        // ---- compute current chunk from prefetched registers ----
        {
            float vx = ax - bx, vy = ay - by, vz = az - bz;
            float dist = sqrtf(vx*vx + vy*vy + vz*vz);
            float inv  = 1.0f / dist;
            float ux = vx*inv, uy = vy*inv, uz = vz*inv;

            const float S3  = 1.7320508075688772f;
            const float S5  = 2.2360679774997896f;
            const float S15 = 3.8729833462074170f;
            float s0 = S3 * ux, s1 = S3 * uy, s2 = S3 * uz;
            float t0 = S15 * ux * uz;
            float t1 = S15 * ux * uy;
            float t2 = S5  * (uy*uy - 0.5f*(ux*ux + uz*uz));
            float t3 = S15 * uy * uz;
            float t4 = 0.5f * S15 * (uz*uz - ux*ux);

            f32x4* pb = (f32x4*)(&sh_pat[c & 1][0]) + t;
#define PW(j, a_, b_, c_, d_) { f32x4 v_; v_.x=a_; v_.y=b_; v_.z=c_; v_.w=d_; \
                                pb[(j) * (PSTRIDE/4)] = v_; }
            PW(0, 1.0f, 1.0f, 1.0f, 1.0f)
            PW(1, s0, s1, s2, s0)
            PW(2, s1, s2, s0, s1)
            PW(3, s2, s0, s1, s2)
            PW(4, t0, t1, t2, t3)
            PW(5, t1, t2, t3, t4)
            PW(6, t2, t3, t4, t0)
            PW(7, t3, t4, t0, t1)
            PW(8, t4, t0, t1, t2)
#undef PW

            // cutoff poly p=5: 1 - 21u^5 + 35u^6 - 15u^7
            float u  = dist * 0.2f;
            float u2 = u*u, u5 = u2*u2*u;
            float f  = 1.0f + u5*(-21.0f + u*(35.0f - 15.0f*u));
            fcut[ecur] = (u < 1.0f) ? f : 0.0f;

            // rbf via Chebyshev recurrence: sin(n*th), th = pi*dist/5
            float th = 0.62831853071795864769f * dist;
            float sn = __sinf(th), cs = __cosf(th);
            float twoc = 2.0f * cs;
            float kk = 0.6324555320336759f * inv;
            float sp = 0.0f, sc = sn;
            float* rb = sh_rbf + t * 20;
#pragma unroll
            for (int q = 0; q < NUM_BASIS; ++q) {
                rb[q] = kk * sc;
                float nx = twoc*sc - sp; sp = sc; sc = nx;
            }
        }

        // ---- prefetch next chunk (loads in flight during store loop) ----
        if (c + 1 < CHUNKS) {
            int en = ((c + 1) * EBLK + blk) * EPB + t;
            s  = eidx[en];
            dn = eidx[N_EDGES + en];
            ax = pos[s*3+1];  ay = pos[s*3+2];  az = pos[s*3+0];
            bx = pos[dn*3+1]; by = pos[dn*3+2]; bz = pos[dn*3+0];
        }

        LDS_BARRIER();     // staging of chunk c visible; stores stay in flight

        // ---- rbf writeout (coalesced, 5 x 128 f4) ----
        {
            const f32x4* ls = (const f32x4*)sh_rbf;
            f32x4* go = (f32x4*)(rbf + (size_t)ebase * NUM_BASIS);
#pragma unroll
            for (int q = 0; q < 5; ++q)
                go[q * EPB + t] = ls[q * EPB + t];
        }

        // ---- rsh store loop ----
        {
            const float* patb = &sh_pat[c & 1][0];
            float* outb = rsh + (size_t)ebase * 480 + (size_t)t * 4;
            int base = 0;
#pragma unroll 1
            for (int i = 0; i < 8; ++i) {
#pragma unroll
                for (int k = 0; k < 15; ++k) {
                    f32x4 v = *(const f32x4*)(patb + base + offs[k]);
                    *(f32x4*)(outb + (size_t)k * 512) = v;
                }
                base += 64;
                outb += 15 * 512;
            }
        }

        LDS_BARRIER();     // ds_reads of pat[c&1]+sh_rbf done; no vmcnt drain
    }
}

extern "C" void kernel_launch(void* const* d_in, const int* in_sizes, int n_in,
                              void* d_out, int out_size, void* d_ws, size_t ws_size,
                              hipStream_t stream) {
    const int*   at_no = (const int*)  d_in[0];
    const float* pos   = (const float*)d_in[1];
    const int*   eidx  = (const int*)  d_in[2];
    const float* embed = (const float*)d_in[3];
    const float* W     = (const float*)d_in[4];
    const float* b     = (const float*)d_in[5];

    float* out      = (float*)d_out;
    float* x_scalar = out;                                   // 16000*128
    float* rbf      = x_scalar + (size_t)N_NODES * NODE_DIM; // 512000*20
    float* fcut     = rbf + (size_t)N_EDGES * NUM_BASIS;     // 512000
    float* rsh      = fcut + N_EDGES;                        // 512000*480

    fused_all_kernel<<<NODE_BLOCKS + EBLK, 128, 0, stream>>>(
        at_no, pos, eidx, embed, W, b, x_scalar, rbf, fcut, rsh);
}